// Round 3
// baseline (779.806 us; speedup 1.0000x reference)
//
#include <hip/hip_runtime.h>
#include <hip/hip_fp16.h>
#include <stdint.h>

#define GENES 5000
#define NH1   4000
#define NH2   2000
#define NH3   1000
#define NPATH 200
#define NLAB  50
#define NROWS 8192
#define KP    100   // genes per pathway
#define RB    6     // rows per block in k_main

typedef _Float16 f16x2 __attribute__((ext_vector_type(2)));
union H2U { unsigned int u; f16x2 v; __half2 h; };

__device__ __forceinline__ float dot2acc(unsigned int a, unsigned int b, float c){
#if __has_builtin(__builtin_amdgcn_fdot2)
    H2U ua; ua.u = a; H2U ub; ub.u = b;
    return __builtin_amdgcn_fdot2(ua.v, ub.v, c, false);
#else
    H2U ua; ua.u = a; H2U ub; ub.u = b;
    float2 fa = __half22float2(ua.h), fb = __half22float2(ub.h);
    return fmaf(fa.x, fb.x, fmaf(fa.y, fb.y, c));
#endif
}

__device__ __forceinline__ unsigned pklo(unsigned xa, unsigned xb){
#if __has_builtin(__builtin_amdgcn_perm)
    return __builtin_amdgcn_perm(xb, xa, 0x05040100u);
#else
    return (xa & 0xffffu) | (xb << 16);
#endif
}
__device__ __forceinline__ unsigned pkhi(unsigned xa, unsigned xb){
#if __has_builtin(__builtin_amdgcn_perm)
    return __builtin_amdgcn_perm(xb, xa, 0x07060302u);
#else
    return (xa >> 16) | (xb & 0xffff0000u);
#endif
}

// ---------------- prep: extract pathway gene indices from m1 ----------------
__global__ void k_idx(const float* __restrict__ m1, int* __restrict__ idx1){
    __shared__ int cnt;
    if (threadIdx.x == 0) cnt = 0;
    __syncthreads();
    const float* row = m1 + (size_t)blockIdx.x * 20 * GENES;
    for (int g = threadIdx.x; g < GENES; g += blockDim.x){
        if (row[g] != 0.0f){
            int pos = atomicAdd(&cnt, 1);
            if (pos < KP) idx1[blockIdx.x * KP + pos] = g;
        }
    }
}

// ---- merged prep: w1 gather (blocks 0..1562) + folds/cones (1563..1829) ----
__global__ void k_prep2(const float* __restrict__ w1, const float* __restrict__ gamma1,
                        const float* __restrict__ rv1, const int* __restrict__ idx1,
                        __half* __restrict__ wg1p,
                        const float* __restrict__ w2, const float* __restrict__ b2,
                        const float* __restrict__ w3, const float* __restrict__ b3,
                        const float* __restrict__ w4, const float* __restrict__ wc,
                        const float* __restrict__ beta1, const float* __restrict__ rm1,
                        const float* __restrict__ gamma2, const float* __restrict__ beta2,
                        const float* __restrict__ rm2, const float* __restrict__ rv2,
                        const float* __restrict__ gamma3, const float* __restrict__ beta3,
                        const float* __restrict__ rm3, const float* __restrict__ rv3,
                        const float* __restrict__ b1,
                        float* __restrict__ bf1, float* __restrict__ bf2,
                        float* __restrict__ bf3,
                        __half* __restrict__ wpk, float* __restrict__ wcT){
    if (blockIdx.x < 1563){
        int tid = blockIdx.x * 256 + threadIdx.x;
        if (tid >= 400000) return;
        int kk  = tid / 8000;
        int rem = tid % 8000;
        int c = rem >> 3;          // c = p*5+g
        int e = rem & 7;           // u*2 + kpar
        int p = c / 5, g = c % 5;
        int u = e >> 1, kpar = e & 1;
        int k = kk * 2 + kpar;
        int j = p * 20 + g * 4 + u;
        int col = idx1[p * KP + k];
        float a = gamma1[j] * rsqrtf(rv1[j] + 1e-5f);
        wg1p[tid] = (__half)(w1[(size_t)j * GENES + col] * a);
        return;
    }
    int t = (blockIdx.x - 1563) * 256 + threadIdx.x;
    if (t < 40000){                      // cone: w2 part, idx i = u2*20+k
        int p = t / 200, i = t % 200;
        int u2 = i / 20, k = i % 20;
        int j = 10 * p + u2;
        float a = gamma2[j] * rsqrtf(rv2[j] + 1e-5f);
        wpk[p * 256 + i] = (__half)(w2[(size_t)j * NH1 + 20 * p + k] * a);
    } else if (t < 50000){               // cone: w3 part at 200 + u3*10 + k
        int i2 = t - 40000;
        int p = i2 / 50, i = i2 % 50;
        int u3 = i / 10, k = i % 10;
        int j = 5 * p + u3;
        float a = gamma3[j] * rsqrtf(rv3[j] + 1e-5f);
        wpk[p * 256 + 200 + i] = (__half)(w3[(size_t)j * NH2 + 10 * p + k] * a);
    } else if (t < 51000){               // cone: w4 part at 250 + k
        int i2 = t - 50000;
        int p = i2 / 5, k = i2 % 5;
        wpk[p * 256 + 250 + k] = (__half)(w4[(size_t)p * NH3 + 5 * p + k]);
    } else if (t < 51200){               // pad slot 255
        int p = t - 51000;
        wpk[p * 256 + 255] = (__half)0.0f;
    } else if (t < 61200){               // wcT[q][n]
        int i = t - 51200;
        int q = i / NLAB, n = i % NLAB;
        wcT[i] = wc[(size_t)n * NPATH + q];
    } else if (t < 65200){               // bf1
        int j = t - 61200;
        float a = gamma1[j] * rsqrtf(rv1[j] + 1e-5f);
        bf1[j] = a * b1[j] + beta1[j] - rm1[j] * a;
    } else if (t < 67200){               // bf2
        int j = t - 65200;
        float a = gamma2[j] * rsqrtf(rv2[j] + 1e-5f);
        bf2[j] = a * b2[j] + beta2[j] - rm2[j] * a;
    } else if (t < 68200){               // bf3
        int j = t - 67200;
        float a = gamma3[j] * rsqrtf(rv3[j] + 1e-5f);
        bf3[j] = a * b3[j] + beta3[j] - rm3[j] * a;
    }
}

// ================= fused: layer1 (sparse) + layers 2..5 cone ================
__global__ __launch_bounds__(256, 2) void k_main(const float* __restrict__ x,
        const int* __restrict__ idx1, const __half* __restrict__ wg1p,
        const float* __restrict__ bf1,
        const __half* __restrict__ wpk, const float* __restrict__ bf2,
        const float* __restrict__ bf3, const float* __restrict__ b4,
        const float* __restrict__ wcT, const float* __restrict__ bc,
        float* __restrict__ out){
    // smem: phase 1 = xs[col][r01,r23,r45] f16, stride 12 B, 60000 B
    //       phase 2 = h1 tile [6 rows][4000 units] f16, 48000 B (reuse)
    __shared__ __align__(16) unsigned char smem[60000];
    __shared__ float scs[RB * NPATH];    // 4.8 KB
    const int t = threadIdx.x;
    const int r0 = blockIdx.x * RB;
    const int rvld = min(RB, NROWS - r0);

    // ---------------- stage x -> f16 LDS ----------------
    for (int c = t; c < GENES; c += 256){
        float v[RB];
        #pragma unroll
        for (int r = 0; r < RB; ++r)
            v[r] = (r < rvld) ? x[(size_t)(r0 + r) * GENES + c] : 0.0f;
        unsigned* d = (unsigned*)(smem + c * 12);
        __half2 h01 = __floats2half2_rn(v[0], v[1]);
        __half2 h23 = __floats2half2_rn(v[2], v[3]);
        __half2 h45 = __floats2half2_rn(v[4], v[5]);
        d[0] = *(unsigned*)&h01; d[1] = *(unsigned*)&h23; d[2] = *(unsigned*)&h45;
    }
    __syncthreads();

    // ---------------- layer 1: 4 passes, results held in regs ----------------
    unsigned h1r[48];
    const int pl = t / 5, g = t % 5;
    if (t < 250){
        #pragma unroll 1
        for (int pass = 0; pass < 4; ++pass){
            const int p = pass * 50 + pl;
            const int2* ip = (const int2*)(idx1 + p * KP);
            const uint4* wp = ((const uint4*)wg1p) + (p * 5 + g);
            float acc[4][RB];
            #pragma unroll
            for (int u = 0; u < 4; ++u)
                #pragma unroll
                for (int r = 0; r < RB; ++r) acc[u][r] = 0.0f;
            // prefetch queues: idx/weights depth 3, LDS-x depth 1
            int2 iv0 = ip[0], iv1 = ip[1], iv2 = ip[2];
            uint4 wv0 = wp[0], wv1 = wp[1000], wv2 = wp[2000];
            uint3 xa0 = *(const uint3*)(smem + iv0.x * 12);
            uint3 xb0 = *(const uint3*)(smem + iv0.y * 12);
            for (int kk = 0; kk < 50; ++kk){
                int nk = kk + 3; nk = (nk > 49) ? 49 : nk;
                int2 ivN = ip[nk];
                uint4 wvN = wp[(size_t)nk * 1000];
                uint3 xa1 = *(const uint3*)(smem + iv1.x * 12);
                uint3 xb1 = *(const uint3*)(smem + iv1.y * 12);
                unsigned pr[RB] = { pklo(xa0.x, xb0.x), pkhi(xa0.x, xb0.x),
                                    pklo(xa0.y, xb0.y), pkhi(xa0.y, xb0.y),
                                    pklo(xa0.z, xb0.z), pkhi(xa0.z, xb0.z) };
                const unsigned wu[4] = {wv0.x, wv0.y, wv0.z, wv0.w};
                #pragma unroll
                for (int u = 0; u < 4; ++u)
                    #pragma unroll
                    for (int r = 0; r < RB; ++r)
                        acc[u][r] = dot2acc(pr[r], wu[u], acc[u][r]);
                iv0 = iv1; iv1 = iv2; iv2 = ivN;
                wv0 = wv1; wv1 = wv2; wv2 = wvN;
                xa0 = xa1; xb0 = xb1;
            }
            const float4 bf = ((const float4*)bf1)[p * 5 + g];
            #pragma unroll
            for (int r = 0; r < RB; ++r){
                __half2 o01 = __floats2half2_rn(fmaxf(acc[0][r] + bf.x, 0.0f),
                                                fmaxf(acc[1][r] + bf.y, 0.0f));
                __half2 o23 = __floats2half2_rn(fmaxf(acc[2][r] + bf.z, 0.0f),
                                                fmaxf(acc[3][r] + bf.w, 0.0f));
                h1r[pass * 12 + r * 2]     = *(unsigned*)&o01;
                h1r[pass * 12 + r * 2 + 1] = *(unsigned*)&o23;
            }
        }
    }
    __syncthreads();               // all xs reads complete -> safe to reuse smem
    if (t < 250){
        #pragma unroll 1
        for (int pass = 0; pass < 4; ++pass){
            const int j0 = (pass * 50 + pl) * 20 + g * 4;
            #pragma unroll
            for (int r = 0; r < RB; ++r){
                uint2 st; st.x = h1r[pass * 12 + r * 2]; st.y = h1r[pass * 12 + r * 2 + 1];
                *(uint2*)(smem + r * 8000 + j0 * 2) = st;
            }
        }
    }
    __syncthreads();

    // ---------------- layers 2..4: register cone, thread = pathway ----------
    if (t < NPATH){
        const int p = t;
        unsigned cw[128];
        const uint4* wp4 = (const uint4*)(wpk + p * 256);
        #pragma unroll
        for (int i = 0; i < 32; ++i){
            uint4 v = wp4[i];
            cw[4*i] = v.x; cw[4*i+1] = v.y; cw[4*i+2] = v.z; cw[4*i+3] = v.w;
        }
        float c2[10], c3[5];
        #pragma unroll
        for (int i = 0; i < 10; ++i) c2[i] = bf2[10 * p + i];
        #pragma unroll
        for (int i = 0; i < 5; ++i)  c3[i] = bf3[5 * p + i];
        const float b4p = b4[p];
        for (int r = 0; r < RB; ++r){
            const uint2* hp = (const uint2*)(smem + r * 8000 + p * 40);
            unsigned h1u[10];
            #pragma unroll
            for (int i = 0; i < 5; ++i){ uint2 v = hp[i]; h1u[2*i] = v.x; h1u[2*i+1] = v.y; }
            unsigned h2u[5];
            #pragma unroll
            for (int i = 0; i < 5; ++i){
                float a0 = c2[2*i], a1 = c2[2*i+1];
                #pragma unroll
                for (int kk = 0; kk < 10; ++kk){
                    a0 = dot2acc(h1u[kk], cw[(2*i) * 10 + kk], a0);
                    a1 = dot2acc(h1u[kk], cw[(2*i+1) * 10 + kk], a1);
                }
                __half2 hh = __floats2half2_rn(fmaxf(a0, 0.f), fmaxf(a1, 0.f));
                h2u[i] = *(unsigned*)&hh;
            }
            float h3f[5];
            #pragma unroll
            for (int u = 0; u < 5; ++u){
                float a = c3[u];
                #pragma unroll
                for (int kk = 0; kk < 5; ++kk)
                    a = dot2acc(h2u[kk], cw[100 + u * 5 + kk], a);
                h3f[u] = fmaxf(a, 0.f);
            }
            unsigned h3u[3];
            __half2 t01 = __floats2half2_rn(h3f[0], h3f[1]); h3u[0] = *(unsigned*)&t01;
            __half2 t23 = __floats2half2_rn(h3f[2], h3f[3]); h3u[1] = *(unsigned*)&t23;
            __half2 t4  = __floats2half2_rn(h3f[4], 0.f);    h3u[2] = *(unsigned*)&t4;
            float a = b4p;
            #pragma unroll
            for (int kk = 0; kk < 3; ++kk)
                a = dot2acc(h3u[kk], cw[125 + kk], a);
            scs[r * NPATH + p] = fmaxf(a, 0.f);
        }
    }
    __syncthreads();

    // ---------------- layer 5: scores @ wc^T + bc ----------------
    for (int o = t; o < RB * NLAB; o += 256){
        int r = o / NLAB, n = o % NLAB;
        if (r0 + r < NROWS){
            float acc2 = bc[n];
            const float* sp = scs + r * NPATH;
            #pragma unroll 8
            for (int q = 0; q < NPATH; ++q)
                acc2 = fmaf(sp[q], wcT[q * NLAB + n], acc2);
            out[(size_t)(r0 + r) * NLAB + n] = acc2;
        }
    }
}

extern "C" void kernel_launch(void* const* d_in, const int* in_sizes, int n_in,
                              void* d_out, int out_size, void* d_ws, size_t ws_size,
                              hipStream_t stream){
    (void)in_sizes; (void)n_in; (void)out_size; (void)ws_size;
    const float* x      = (const float*)d_in[0];
    const float* w1     = (const float*)d_in[1];
    const float* b1     = (const float*)d_in[2];
    const float* m1     = (const float*)d_in[3];
    const float* w2     = (const float*)d_in[4];
    const float* b2     = (const float*)d_in[5];
    const float* w3     = (const float*)d_in[7];
    const float* b3     = (const float*)d_in[8];
    const float* w4     = (const float*)d_in[10];
    const float* b4     = (const float*)d_in[11];
    const float* gamma1 = (const float*)d_in[13];
    const float* beta1  = (const float*)d_in[14];
    const float* rm1    = (const float*)d_in[15];
    const float* rv1    = (const float*)d_in[16];
    const float* gamma2 = (const float*)d_in[17];
    const float* beta2  = (const float*)d_in[18];
    const float* rm2    = (const float*)d_in[19];
    const float* rv2    = (const float*)d_in[20];
    const float* gamma3 = (const float*)d_in[21];
    const float* beta3  = (const float*)d_in[22];
    const float* rm3    = (const float*)d_in[23];
    const float* rv3    = (const float*)d_in[24];
    const float* wc     = (const float*)d_in[25];
    const float* bc     = (const float*)d_in[26];

    char* ws = (char*)d_ws;
    size_t off = 0;
    int*    idx1  = (int*)  (ws + off);  off += (size_t)NPATH * KP * 4;   // 80 KB
    __half* wg1p  = (__half*)(ws + off); off += (size_t)400000 * 2;       // 800 KB
    float*  bf1   = (float*)(ws + off);  off += (size_t)NH1 * 4;
    float*  bf2   = (float*)(ws + off);  off += (size_t)NH2 * 4;
    float*  bf3   = (float*)(ws + off);  off += (size_t)NH3 * 4;
    __half* wpk   = (__half*)(ws + off); off += (size_t)NPATH * 256 * 2;  // 102.4 KB
    float*  wcT   = (float*)(ws + off);  off += (size_t)NPATH * NLAB * 4; // 40 KB

    const int nblk = (NROWS + RB - 1) / RB;   // 1366
    hipLaunchKernelGGL(k_idx,   dim3(NPATH),  dim3(256), 0, stream, m1, idx1);
    hipLaunchKernelGGL(k_prep2, dim3(1830),   dim3(256), 0, stream,
                       w1, gamma1, rv1, idx1, wg1p,
                       w2, b2, w3, b3, w4, wc,
                       beta1, rm1, gamma2, beta2, rm2, rv2,
                       gamma3, beta3, rm3, rv3, b1,
                       bf1, bf2, bf3, wpk, wcT);
    hipLaunchKernelGGL(k_main,  dim3(nblk),   dim3(256), 0, stream,
                       x, idx1, wg1p, bf1, wpk, bf2, bf3, b4, wcT, bc, (float*)d_out);
}